// Round 6
// baseline (144.753 us; speedup 1.0000x reference)
//
#include <hip/hip_runtime.h>

// out[b,s,f] = in1[b,s,f] * w[f] + in2[b,s,f] * (1 - w[f])
// B=4, S=4096, F=4096 -> 67,108,864 f32 = 16,777,216 vec4. Memory-bound.
//
// Model (R5 post-mortem): all read+write traffic (768 MB: 512 MB reads of
// which ~half are L3-hits, 256 MB writes) crosses the XCD fabric, whose
// practical ceiling ~6.3 TB/s -> floor ~122 us. R3 = 139.6 us. Remaining gap
// is issue-side: R3 loaded the FULL 16 KB weight vector per block (4 weight
// vec4 per thread = 1/3 of all load instructions, ~262 MB of L1/L2 reads).
//
// R6: 1024-thread blocks, 4 rows (4096 vec4) per block. Thread t's four
// positions {t, t+1024, t+2048, t+3072} all have row-offset t -> ONE weight
// vec4 per thread serves all 4 outputs. 8 a/b loads issued pairwise so
// compute i waits only on the oldest outstanding pair. (1-w) hoisted.

typedef float fvec4 __attribute__((ext_vector_type(4)));

__global__ __launch_bounds__(1024) void merger_kernel(
    const fvec4* __restrict__ a,
    const fvec4* __restrict__ b,
    const fvec4* __restrict__ w,
    fvec4* __restrict__ out) {
    const int t = threadIdx.x;
    const int c = blockIdx.x * 4096 + t;  // 4 rows of 1024 vec4 per block

    const fvec4 wv = w[t];        // row-offset == t for all 4 positions
    const fvec4 mw = 1.0f - wv;   // hoisted

    // 8 independent a/b loads, pairwise order -> minimal vmcnt per consumer.
    const fvec4 a0 = a[c];         const fvec4 b0 = b[c];
    const fvec4 a1 = a[c + 1024];  const fvec4 b1 = b[c + 1024];
    const fvec4 a2 = a[c + 2048];  const fvec4 b2 = b[c + 2048];
    const fvec4 a3 = a[c + 3072];  const fvec4 b3 = b[c + 3072];

    fvec4 o;
    o = a0 * wv + b0 * mw; __builtin_nontemporal_store(o, &out[c]);
    o = a1 * wv + b1 * mw; __builtin_nontemporal_store(o, &out[c + 1024]);
    o = a2 * wv + b2 * mw; __builtin_nontemporal_store(o, &out[c + 2048]);
    o = a3 * wv + b3 * mw; __builtin_nontemporal_store(o, &out[c + 3072]);
}

extern "C" void kernel_launch(void* const* d_in, const int* in_sizes, int n_in,
                              void* d_out, int out_size, void* d_ws, size_t ws_size,
                              hipStream_t stream) {
    const fvec4* a = (const fvec4*)d_in[0];
    const fvec4* b = (const fvec4*)d_in[1];
    const fvec4* w = (const fvec4*)d_in[2];
    fvec4* out = (fvec4*)d_out;
    // 16,777,216 vec4 total; 4096 vec4 (4 rows) per 1024-thread block.
    const int grid = out_size / (4 * 4096);  // 4096 blocks, exact cover
    merger_kernel<<<grid, 1024, 0, stream>>>(a, b, w, out);
}

// Round 7
// 139.816 us; speedup vs baseline: 1.0353x; 1.0353x over previous
//
#include <hip/hip_runtime.h>

// out[b,s,f] = in1[b,s,f] * w[f] + in2[b,s,f] * (1 - w[f])
// B=4, S=4096, F=4096 -> 67,108,864 f32 = 16,777,216 vec4. Memory-bound.
//
// Status: R3/R5/R6 (three distinct structures) converge at 139.6-144.8 us
// with traffic at the capacity-constrained minimum (262 MB fetch + 262 MB
// write HBM; 50% L3 hit = the statistical max for 512 MB streaming through
// 256 MB random-replacement L3). VALU ~3%, no conflicts, occupancy healthy.
// Delivered BW 5.5 TB/s = 87% of the 6.29 TB/s copy ubench.
//
// R7: single-variable A/B vs R3 (the best measured): plain stores instead of
// __builtin_nontemporal_store. Tests whether the TCC nontemporal/no-allocate
// write path write-combines worse than cached write-back. Everything else is
// byte-identical to R3.

typedef float fvec4 __attribute__((ext_vector_type(4)));

__global__ __launch_bounds__(256) void merger_kernel(
    const fvec4* __restrict__ a,
    const fvec4* __restrict__ b,
    const fvec4* __restrict__ w,
    fvec4* __restrict__ out) {
    const int t = threadIdx.x;
    const int base = blockIdx.x * 1024 + t;

    // Weight fragments: block-invariant addresses, L1-hot after first touch.
    const fvec4 wv0 = w[t];
    const fvec4 wv1 = w[t + 256];
    const fvec4 wv2 = w[t + 512];
    const fvec4 wv3 = w[t + 768];

    // 8 independent global loads in flight.
    const fvec4 av0 = a[base];
    const fvec4 av1 = a[base + 256];
    const fvec4 av2 = a[base + 512];
    const fvec4 av3 = a[base + 768];
    const fvec4 bv0 = b[base];
    const fvec4 bv1 = b[base + 256];
    const fvec4 bv2 = b[base + 512];
    const fvec4 bv3 = b[base + 768];

    const fvec4 o0 = av0 * wv0 + bv0 * (1.0f - wv0);
    const fvec4 o1 = av1 * wv1 + bv1 * (1.0f - wv1);
    const fvec4 o2 = av2 * wv2 + bv2 * (1.0f - wv2);
    const fvec4 o3 = av3 * wv3 + bv3 * (1.0f - wv3);

    out[base]       = o0;
    out[base + 256] = o1;
    out[base + 512] = o2;
    out[base + 768] = o3;
}

extern "C" void kernel_launch(void* const* d_in, const int* in_sizes, int n_in,
                              void* d_out, int out_size, void* d_ws, size_t ws_size,
                              hipStream_t stream) {
    const fvec4* a = (const fvec4*)d_in[0];
    const fvec4* b = (const fvec4*)d_in[1];
    const fvec4* w = (const fvec4*)d_in[2];
    fvec4* out = (fvec4*)d_out;
    const int grid = out_size / (4 * 1024);  // 16384 blocks, exact cover
    merger_kernel<<<grid, 256, 0, stream>>>(a, b, w, out);
}